// Round 8
// baseline (612.010 us; speedup 1.0000x reference)
//
#include <hip/hip_runtime.h>
#include <hip/hip_bf16.h>
#include <math.h>

#define NB 4
#define LL 16384
#define CC 256
#define NHD 8
#define DH 32
#define MROWS (NB*LL)   // 65536

typedef __hip_bfloat16 bf16;
typedef __attribute__((ext_vector_type(8))) short short8;
typedef __attribute__((ext_vector_type(4))) float floatx4;

__device__ __forceinline__ float u2f(unsigned short u) {
  return __uint_as_float(((unsigned)u) << 16);
}
__device__ __forceinline__ unsigned short f2u(float f) {
  bf16 t = __float2bfloat16(f);
  unsigned short u;
  __builtin_memcpy(&u, &t, 2);
  return u;
}

// ---------------- f32 -> bf16 bulk convert (8 elems/thread) --------------
__global__ __launch_bounds__(256) void convert_kernel(
    const float* __restrict__ in, bf16* __restrict__ out, int n8)
{
  int i = blockIdx.x*256 + threadIdx.x;
  if (i >= n8) return;
  const float4* p = (const float4*)in + (size_t)i*2;
  float4 f0 = p[0], f1 = p[1];
  unsigned short t[8] = {f2u(f0.x),f2u(f0.y),f2u(f0.z),f2u(f0.w),
                         f2u(f1.x),f2u(f1.y),f2u(f1.z),f2u(f1.w)};
  *(uint4*)(out + (size_t)i*8) = *(uint4*)t;
}

// ---------------- all weights f32 -> bf16, one dispatch ------------------
__global__ __launch_bounds__(256) void convert_weights_kernel(
    const float* __restrict__ Wq, const float* __restrict__ Wk,
    const float* __restrict__ Wv, const float* __restrict__ Wm,
    const float* __restrict__ W1, const float* __restrict__ W2,
    bf16* __restrict__ dst)
{
  int i = blockIdx.x*256 + threadIdx.x;    // 8-elem unit; total 81920 units
  const float* src; int off8;
  if      (i < 8192)  { src = Wq; off8 = i; }
  else if (i < 16384) { src = Wk; off8 = i-8192; }
  else if (i < 24576) { src = Wv; off8 = i-16384; }
  else if (i < 32768) { src = Wm; off8 = i-24576; }
  else if (i < 65536) { src = W1; off8 = i-32768; }
  else                { src = W2; off8 = i-65536; }
  const float4* p = (const float4*)src + (size_t)off8*2;
  float4 f0 = p[0], f1 = p[1];
  unsigned short t[8] = {f2u(f0.x),f2u(f0.y),f2u(f0.z),f2u(f0.w),
                         f2u(f1.x),f2u(f1.y),f2u(f1.z),f2u(f1.w)};
  *(uint4*)(dst + (size_t)i*8) = *(uint4*)t;
}

// ---------------- m97-style 4-wave 128x128 MFMA GEMM ---------------------
// C[M,N] = epi( A[M,K] @ B[N,K]^T ), all bf16.  BK=32.
// Changes vs the proven 68.7us baseline:
//  * B is NOT staged in LDS: each wave loads its 4 B fragments straight
//    from global (L2-resident weights) into regs before the barrier.
//    Halves LDS port traffic and the vmcnt drain depth at the barrier.
//  * A tile LDS layout XOR-swizzled: slot(row,q') holds global unit
//    q'^((row>>1)&3). Staged with linear LDS dest + pre-permuted global
//    source (permutation stays inside each row's 64B segment -> same
//    coalescing). Fragment ds_read_b128 becomes bank-conflict-free.
// EPI: 0 none, 1 relu, 2 elu+1+RoPE (N=256),
//      3 fused k|v: bn<2 -> rope to C (stride 256), bn>=2 -> plain to C2.
template<int EPI>
__global__ __launch_bounds__(256) void gemm_m97(
    const bf16* __restrict__ A0, int K0, const bf16* __restrict__ A1,
    const bf16* __restrict__ B, bf16* __restrict__ C, bf16* __restrict__ C2,
    int M, int N, int K)
{
  __shared__ __align__(16) unsigned short As[4096];   // 8 KB: 128 rows x 4 units
  const int tid  = threadIdx.x;
  const int lane = tid & 63, wave = tid >> 6;
  const int wm = wave & 1, wn = wave >> 1;
  const int l15 = lane & 15, quad = lane >> 4;

  // swizzle: blocks with same bm, all bn sit 8 apart -> same XCD L2 shares A
  const int nbn = N >> 7;                       // 2 or 4
  const int sh  = (nbn == 2) ? 4 : 5;           // log2(8*nbn)
  const int w   = blockIdx.x & ((1 << sh) - 1);
  const int g   = blockIdx.x >> sh;
  const int bm  = g*8 + (w & 7);
  const int bn  = w >> 3;

  const bf16* bBase = B + (size_t)(bn*128 + wn*64 + l15)*K;  // B frag rows
  const int swz = quad ^ ((l15 >> 1) & 3);      // A read slot (row-invariant)

  floatx4 acc[4][4] = {};

  for (int kt = 0; kt < K; kt += 32) {
    const bf16* aSrc; int lda, kof;
    if (kt < K0) { aSrc = A0; lda = K0;     kof = kt; }
    else         { aSrc = A1; lda = K - K0; kof = kt - K0; }
    // stage A tile (128x32) with XOR-swizzled source, linear LDS dest
    #pragma unroll
    for (int m = 0; m < 2; m++) {
      int U = m*256 + tid;                 // unit id 0..511
      int row = U >> 2, q = U & 3;
      int gq = q ^ ((row >> 1) & 3);       // pre-permuted source unit
      const bf16* gp = aSrc + (size_t)(bm*128 + row)*lda + kof + gq*8;
      __builtin_amdgcn_global_load_lds(
          (const __attribute__((address_space(1))) void*)gp,
          (__attribute__((address_space(3))) void*)(As + (size_t)U*8),
          16, 0, 0);
    }
    // B fragments direct from global (L2-hot weights)
    short8 b[4];
    #pragma unroll
    for (int j = 0; j < 4; j++)
      b[j] = *(const short8*)(bBase + (size_t)(j*16)*K + kt + quad*8);
    __syncthreads();                        // drains vmcnt -> A landed
    short8 a[4];
    #pragma unroll
    for (int i = 0; i < 4; i++)
      a[i] = *(const short8*)&As[((wm*64 + i*16 + l15)*4 + swz)*8];
    #pragma unroll
    for (int i = 0; i < 4; i++)
      #pragma unroll
      for (int j = 0; j < 4; j++)
        acc[i][j] = __builtin_amdgcn_mfma_f32_16x16x32_bf16(a[i], b[j], acc[i][j], 0, 0, 0);
    __syncthreads();
  }

  // epilogue: C/D layout col=lane&15, row=quad*4+reg
  const int row0 = bm*128 + wm*64 + quad*4;
  const int col0 = bn*128 + wn*64 + l15;
  const bool doRope = (EPI == 2) || (EPI == 3 && bn < 2);
  if (doRope) {
    // pair-channel constants, fixed per lane (col0&31 == l15)
    const int pp_e = l15 >> 1;        // j even
    const int pp_o = pp_e + 8;        // j odd
    const int par  = pp_e & 1;        // i-angle (0) vs j-angle (1)
    const float dv_e = __expf(-1.15129254650564f * (float)(pp_e >> 1));
    const float dv_o = __expf(-1.15129254650564f * (float)(pp_o >> 1));
    const float sgn = (l15 & 1) ? 1.f : -1.f;
    #pragma unroll
    for (int i = 0; i < 4; i++) {
      #pragma unroll
      for (int r = 0; r < 4; r++) {
        int row = row0 + i*16 + r;
        int l = row & (LL-1);
        float pos = par ? (float)((l & 127) + 1) : (float)((l >> 7) + 1);
        float ae = pos * dv_e, ao = pos * dv_o;
        float se = __sinf(ae), ce = __cosf(ae);
        float so = __sinf(ao), co = __cosf(ao);
        #pragma unroll
        for (int j = 0; j < 4; j++) {
          float s = (j & 1) ? so : se;
          float c = (j & 1) ? co : ce;
          float v = acc[i][j][r];
          v = v > 0.f ? v + 1.f : __expf(v);   // elu+1
          float p = __shfl_xor(v, 1, 64);      // pair partner channel
          float o = fmaf(v, c, sgn * p * s);
          int stride = (EPI == 3) ? 256 : N;
          C[(size_t)row*stride + (col0 + j*16)] = __float2bfloat16(o);
        }
      }
    }
  } else if (EPI == 3) {
    // v half: plain store to C2 at col-256, stride 256
    #pragma unroll
    for (int i = 0; i < 4; i++)
      #pragma unroll
      for (int j = 0; j < 4; j++)
        #pragma unroll
        for (int r = 0; r < 4; r++)
          C2[(size_t)(row0 + i*16 + r)*256 + (col0 - 256 + j*16)] =
              __float2bfloat16(acc[i][j][r]);
  } else {
    #pragma unroll
    for (int i = 0; i < 4; i++)
      #pragma unroll
      for (int j = 0; j < 4; j++)
        #pragma unroll
        for (int r = 0; r < 4; r++) {
          float v = acc[i][j][r];
          if (EPI == 1) v = fmaxf(v, 0.f);
          C[(size_t)(row0 + i*16 + r)*N + (col0 + j*16)] = __float2bfloat16(v);
        }
  }
}

// ---------------- KV partials: no atomics --------------------------------
#define KVPAD 36   // f32 row stride: 144 B = 16B-aligned, breaks bank cycle
__global__ __launch_bounds__(256) void kv_kernel(
    const bf16* __restrict__ Kr, const bf16* __restrict__ V,
    float* __restrict__ KVp, float* __restrict__ Ksp)
{
  __shared__ __align__(16) float Kf[128*KVPAD];  // 18 KB
  __shared__ __align__(16) float Vf[128*KVPAD];  // 18 KB
  const int nh = blockIdx.x;               // n*8+h
  const int n = nh >> 3, h = nh & 7;
  const int cs = blockIdx.y;               // 32 chunks of 512 rows
  const int s0 = cs << 9;
  const int tid = threadIdx.x;
  const int d = tid >> 3, e0 = (tid & 7) << 2;

  float acc0 = 0.f, acc1 = 0.f, acc2 = 0.f, acc3 = 0.f, ks = 0.f;

  for (int sub = 0; sub < 4; sub++) {
    const int sb = s0 + sub*128;
    #pragma unroll
    for (int u = tid; u < 512; u += 256) {
      int row = u >> 2, d0 = (u & 3) << 3;
      size_t g = (((size_t)(n*LL + sb + row)*NHD + h) << 5) + d0;
      short8 k8 = *(const short8*)(Kr + g);
      short8 v8 = *(const short8*)(V + g);
      float* kp = &Kf[row*KVPAD + d0];
      float* vp = &Vf[row*KVPAD + d0];
      float4 ka = {u2f((unsigned short)k8[0]), u2f((unsigned short)k8[1]),
                   u2f((unsigned short)k8[2]), u2f((unsigned short)k8[3])};
      float4 kb = {u2f((unsigned short)k8[4]), u2f((unsigned short)k8[5]),
                   u2f((unsigned short)k8[6]), u2f((unsigned short)k8[7])};
      float4 va = {u2f((unsigned short)v8[0]), u2f((unsigned short)v8[1]),
                   u2f((unsigned short)v8[2]), u2f((unsigned short)v8[3])};
      float4 vb = {u2f((unsigned short)v8[4]), u2f((unsigned short)v8[5]),
                   u2f((unsigned short)v8[6]), u2f((unsigned short)v8[7])};
      *(float4*)kp = ka; *(float4*)(kp+4) = kb;
      *(float4*)vp = va; *(float4*)(vp+4) = vb;
    }
    __syncthreads();
    #pragma unroll 8
    for (int ss = 0; ss < 128; ss++) {
      float kd = Kf[ss*KVPAD + d];                     // broadcast (8 lanes)
      float4 v4 = *(const float4*)&Vf[ss*KVPAD + e0];  // broadcast (8 lanes)
      acc0 = fmaf(kd, v4.x, acc0);
      acc1 = fmaf(kd, v4.y, acc1);
      acc2 = fmaf(kd, v4.z, acc2);
      acc3 = fmaf(kd, v4.w, acc3);
      ks += kd;
    }
    __syncthreads();
  }

  float* kvp = KVp + (((size_t)nh << 5) + cs) * 1024 + (tid << 2);
  kvp[0] = acc0; kvp[1] = acc1; kvp[2] = acc2; kvp[3] = acc3;
  if ((tid & 7) == 0) Ksp[(((size_t)nh << 5) + cs) * 32 + d] = ks;
}

// ---------------- reduce partials -> KV[nh][1024], Ksum[nh][32] ----------
__global__ __launch_bounds__(256) void reduce_kv_kernel(
    const float* __restrict__ KVp, const float* __restrict__ Ksp,
    float* __restrict__ KV, float* __restrict__ Ksum)
{
  const int nh = blockIdx.x;
  const int tid = threadIdx.x;
  float4 acc = {0.f,0.f,0.f,0.f};
  #pragma unroll 8
  for (int cs = 0; cs < 32; cs++) {
    float4 p = *(const float4*)(KVp + (((size_t)nh << 5) + cs) * 1024 + (tid << 2));
    acc.x += p.x; acc.y += p.y; acc.z += p.z; acc.w += p.w;
  }
  *(float4*)(KV + ((size_t)nh << 10) + (tid << 2)) = acc;
  if (tid < 32) {
    float s = 0.f;
    #pragma unroll 8
    for (int cs = 0; cs < 32; cs++)
      s += Ksp[(((size_t)nh << 5) + cs) * 32 + tid];
    Ksum[(nh << 5) + tid] = s;
  }
}

// ---------------- out[l,h,e] = (Q_h . KV_h[:,e]) / (Q_h . Ksum_h + eps) ---
__global__ __launch_bounds__(256) void attn_out_kernel(
    const bf16* __restrict__ Qr, const float* __restrict__ KV,
    const float* __restrict__ Ksum, bf16* __restrict__ Out)
{
  __shared__ float KVs[8192];
  __shared__ float Kss[256];
  __shared__ float Qs[16][256];
  const int blk = blockIdx.x;            // 4096 blocks, 16 rows each
  const int n = blk >> 10;               // 1024 blocks per batch
  const int tid = threadIdx.x;
  const size_t rowBase = (size_t)blk * 16;
  for (int i = tid; i < 8192; i += 256) KVs[i] = KV[((size_t)n << 13) + i];
  Kss[tid] = Ksum[(n << 8) + tid];
  #pragma unroll
  for (int it = 0; it < 2; it++) {
    int i = it*256 + tid;                // 8-elem unit, 512 units total
    short8 u = *(const short8*)(Qr + (rowBase << 8) + (size_t)i*8);
    float* qp = ((float*)Qs) + (size_t)i*8;
    #pragma unroll
    for (int j = 0; j < 8; j++) qp[j] = u2f((unsigned short)u[j]);
  }
  __syncthreads();
  const int h = tid >> 5, e = tid & 31;
  const float* kvh = &KVs[(h << 10) + e];
  const float* ksh = &Kss[h << 5];
  for (int r = 0; r < 16; r++) {
    const float* qh = &Qs[r][h << 5];
    float denom = 1e-6f;
    float num = 0.f;
    #pragma unroll
    for (int d = 0; d < 32; d++) {
      float qd = qh[d];
      denom = fmaf(qd, ksh[d], denom);
      num   = fmaf(qd, kvh[d << 5], num);
    }
    Out[((rowBase + r) << 8) + tid] = __float2bfloat16(num / denom);
  }
}

// ---------------- LayerNorm over 256, bf16 ws in/out, f32 params ---------
__global__ __launch_bounds__(256) void ln_kernel(
    const bf16* __restrict__ X, const float* __restrict__ g, const float* __restrict__ b,
    bf16* __restrict__ Out)
{
  __shared__ float ps[4], psq[4], stat[2];
  int row = blockIdx.x, tid = threadIdx.x;
  float v = __bfloat162float(X[((size_t)row << 8) + tid]);
  float s = v, sq = v*v;
  #pragma unroll
  for (int o = 32; o > 0; o >>= 1) {
    s  += __shfl_down(s, o, 64);
    sq += __shfl_down(sq, o, 64);
  }
  if ((tid & 63) == 0) { ps[tid>>6] = s; psq[tid>>6] = sq; }
  __syncthreads();
  if (tid == 0) {
    float S = ps[0]+ps[1]+ps[2]+ps[3];
    float SQ = psq[0]+psq[1]+psq[2]+psq[3];
    float mean = S * (1.f/256.f);
    float var = SQ * (1.f/256.f) - mean*mean;
    stat[0] = mean; stat[1] = rsqrtf(var + 1e-5f);
  }
  __syncthreads();
  float mean = stat[0], rstd = stat[1];
  Out[((size_t)row << 8) + tid] = __float2bfloat16(
      (v - mean)*rstd*g[tid] + b[tid]);
}

// ---------------- final: out = x + LN(h2), f32 x/out ---------------------
__global__ __launch_bounds__(256) void ln_add_kernel(
    const bf16* __restrict__ X, const float* __restrict__ g, const float* __restrict__ b,
    const float* __restrict__ xin, float* __restrict__ Out)
{
  __shared__ float ps[4], psq[4], stat[2];
  int row = blockIdx.x, tid = threadIdx.x;
  size_t idx = ((size_t)row << 8) + tid;
  float v = __bfloat162float(X[idx]);
  float s = v, sq = v*v;
  #pragma unroll
  for (int o = 32; o > 0; o >>= 1) {
    s  += __shfl_down(s, o, 64);
    sq += __shfl_down(sq, o, 64);
  }
  if ((tid & 63) == 0) { ps[tid>>6] = s; psq[tid>>6] = sq; }
  __syncthreads();
  if (tid == 0) {
    float S = ps[0]+ps[1]+ps[2]+ps[3];
    float SQ = psq[0]+psq[1]+psq[2]+psq[3];
    float mean = S * (1.f/256.f);
    float var = SQ * (1.f/256.f) - mean*mean;
    stat[0] = mean; stat[1] = rsqrtf(var + 1e-5f);
  }
  __syncthreads();
  float mean = stat[0], rstd = stat[1];
  float lnv = (v - mean)*rstd*g[tid] + b[tid];
  Out[idx] = xin[idx] + lnv;
}

extern "C" void kernel_launch(void* const* d_in, const int* in_sizes, int n_in,
                              void* d_out, int out_size, void* d_ws, size_t ws_size,
                              hipStream_t stream) {
  const float* x   = (const float*)d_in[0];
  const float* src = (const float*)d_in[1];
  const float* Wq  = (const float*)d_in[2];
  const float* Wk  = (const float*)d_in[3];
  const float* Wv  = (const float*)d_in[4];
  const float* Wm  = (const float*)d_in[5];
  const float* W1  = (const float*)d_in[6];
  const float* W2  = (const float*)d_in[7];
  const float* g1  = (const float*)d_in[8];
  const float* b1  = (const float*)d_in[9];
  const float* g2  = (const float*)d_in[10];
  const float* b2  = (const float*)d_in[11];
  float* out = (float*)d_out;

  bf16* ws = (bf16*)d_ws;
  const size_t BUFH = (size_t)MROWS * CC;   // 16,777,216 bf16 = 32 MB
  bf16* R0 = ws;               // xb (live until W1 gemm)
  bf16* R1 = ws + BUFH;        // sb -> q -> h1(lo)
  bf16* R2 = ws + 2*BUFH;      // k -> attn -> h1(hi)
  bf16* R3 = ws + 3*BUFH;      // v -> msg -> h2
  bf16* WB = ws + 4*BUFH;      // bf16 weights, 655360 elems (1.25 MB)
  bf16* wq = WB, *wk = WB+65536, *wv = WB+131072, *wm = WB+196608,
      *w1 = WB+262144, *w2 = WB+524288;
  float* KV   = (float*)(WB + 655360);      // 32768 f32
  float* Ksum = KV + NB*NHD*DH*DH;          // 1024 f32
  // KV partials live in d_out (64 MB, overwritten only by final ln_add):
  float* KVp = out;                         // 32*32*1024 f32 = 4 MB
  float* Ksp = out + 32*32*1024;            // 32*32*32 f32 = 128 KB

  dim3 blk(256);
  const int n8 = MROWS*CC/8;
  convert_kernel<<<(n8+255)/256, blk, 0, stream>>>(x,   R0, n8);
  convert_kernel<<<(n8+255)/256, blk, 0, stream>>>(src, R1, n8);
  convert_weights_kernel<<<320, blk, 0, stream>>>(Wq, Wk, Wv, Wm, W1, W2, WB);

  const int G256 = (MROWS/128)*(CC/128);    // 1024 blocks
  const int G512 = (MROWS/128)*(2*CC/128);  // 2048 blocks
  // fused: [k|v] = sb @ [wk;wv]^T -> k(rope)->R2, v->R3 (wk,wv contiguous)
  gemm_m97<3><<<G512, blk, 0, stream>>>(R1, CC, nullptr, wk, R2, R3, MROWS, 2*CC, CC);
  // KV + Ksum via partials (no atomics)
  kv_kernel<<<dim3(NB*NHD, 32), blk, 0, stream>>>(R2, R3, KVp, Ksp);
  reduce_kv_kernel<<<NB*NHD, blk, 0, stream>>>(KVp, Ksp, KV, Ksum);
  // q = rope(elu(xb@Wq^T)+1) -> R1 (sb dead)
  gemm_m97<2><<<G256, blk, 0, stream>>>(R0, CC, nullptr, wq, R1, nullptr, MROWS, CC, CC);
  // attn: q(R1) -> R2 (k dead)
  attn_out_kernel<<<MROWS/16, blk, 0, stream>>>(R1, KV, Ksum, R2);
  // msg = LN1(attn @ Wm^T): attn(R2) -> R3 (v dead)
  gemm_m97<0><<<G256, blk, 0, stream>>>(R2, CC, nullptr, wm, R3, nullptr, MROWS, CC, CC);
  ln_kernel<<<MROWS, blk, 0, stream>>>(R3, g1, b1, R3);
  // h1 = relu([xb(R0) | msg(R3)] @ W1^T) -> R1..R2 (64 MB contiguous)
  gemm_m97<1><<<G512, blk, 0, stream>>>(R0, CC, R3, w1, R1, nullptr, MROWS, 2*CC, 2*CC);
  // h2 = h1(R1,K=512) @ W2^T -> R3 (msg dead)
  gemm_m97<0><<<G256, blk, 0, stream>>>(nullptr, 0, R1, w2, R3, nullptr, MROWS, CC, 2*CC);
  // out = x + LN2(h2)
  ln_add_kernel<<<MROWS, blk, 0, stream>>>(R3, g2, b2, x, out);
}

// Round 9
// 538.392 us; speedup vs baseline: 1.1367x; 1.1367x over previous
//
#include <hip/hip_runtime.h>
#include <hip/hip_bf16.h>
#include <math.h>

#define NB 4
#define LL 16384
#define CC 256
#define NHD 8
#define DH 32
#define MROWS (NB*LL)   // 65536

typedef __hip_bfloat16 bf16;
typedef __attribute__((ext_vector_type(8))) short short8;
typedef __attribute__((ext_vector_type(4))) float floatx4;

__device__ __forceinline__ float u2f(unsigned short u) {
  return __uint_as_float(((unsigned)u) << 16);
}
__device__ __forceinline__ unsigned short f2u(float f) {
  bf16 t = __float2bfloat16(f);
  unsigned short u;
  __builtin_memcpy(&u, &t, 2);
  return u;
}

// ---------------- f32 -> bf16 bulk convert (8 elems/thread) --------------
__global__ __launch_bounds__(256) void convert_kernel(
    const float* __restrict__ in, bf16* __restrict__ out, int n8)
{
  int i = blockIdx.x*256 + threadIdx.x;
  if (i >= n8) return;
  const float4* p = (const float4*)in + (size_t)i*2;
  float4 f0 = p[0], f1 = p[1];
  unsigned short t[8] = {f2u(f0.x),f2u(f0.y),f2u(f0.z),f2u(f0.w),
                         f2u(f1.x),f2u(f1.y),f2u(f1.z),f2u(f1.w)};
  *(uint4*)(out + (size_t)i*8) = *(uint4*)t;
}

// ---------------- all weights f32 -> bf16, one dispatch ------------------
__global__ __launch_bounds__(256) void convert_weights_kernel(
    const float* __restrict__ Wq, const float* __restrict__ Wk,
    const float* __restrict__ Wv, const float* __restrict__ Wm,
    const float* __restrict__ W1, const float* __restrict__ W2,
    bf16* __restrict__ dst)
{
  int i = blockIdx.x*256 + threadIdx.x;    // 8-elem unit; total 81920 units
  const float* src; int off8;
  if      (i < 8192)  { src = Wq; off8 = i; }
  else if (i < 16384) { src = Wk; off8 = i-8192; }
  else if (i < 24576) { src = Wv; off8 = i-16384; }
  else if (i < 32768) { src = Wm; off8 = i-24576; }
  else if (i < 65536) { src = W1; off8 = i-32768; }
  else                { src = W2; off8 = i-65536; }
  const float4* p = (const float4*)src + (size_t)off8*2;
  float4 f0 = p[0], f1 = p[1];
  unsigned short t[8] = {f2u(f0.x),f2u(f0.y),f2u(f0.z),f2u(f0.w),
                         f2u(f1.x),f2u(f1.y),f2u(f1.z),f2u(f1.w)};
  *(uint4*)(dst + (size_t)i*8) = *(uint4*)t;
}

// ---------------- m97-style 4-wave 128x128 MFMA GEMM ---------------------
// C[M,N] = epi( A[M,K] @ B[N,K]^T ), all bf16.  BK=32.
// Round-0 proven staging choreography (A AND B via global_load_lds, one
// vmcnt-draining __syncthreads per step) + round-8 proven XOR swizzle on
// BOTH tiles: LDS dest linear (unit u at u*16B), global source unit
// gq = q ^ ((row>>1)&3) (permutation inside each row's 64B segment ->
// same coalescing), fragment read slot swz = quad ^ ((l15>>1)&3).
// Measured (r8): SQ_LDS_BANK_CONFLICT 4.19M -> 0.
// EPI: 0 none, 1 relu, 2 elu+1+RoPE (N=256),
//      3 fused k|v: bn<2 -> rope to C (stride 256), bn>=2 -> plain to C2.
template<int EPI>
__global__ __launch_bounds__(256) void gemm_m97(
    const bf16* __restrict__ A0, int K0, const bf16* __restrict__ A1,
    const bf16* __restrict__ B, bf16* __restrict__ C, bf16* __restrict__ C2,
    int M, int N, int K)
{
  __shared__ __align__(16) unsigned short As[128*32];  // 8 KB
  __shared__ __align__(16) unsigned short Bs[128*32];  // 8 KB
  const int tid  = threadIdx.x;
  const int lane = tid & 63, wave = tid >> 6;
  const int wm = wave & 1, wn = wave >> 1;
  const int l15 = lane & 15, quad = lane >> 4;

  // swizzle: blocks with same bm, all bn sit 8 apart -> same XCD L2 shares A
  const int nbn = N >> 7;                       // 2 or 4
  const int sh  = (nbn == 2) ? 4 : 5;           // log2(8*nbn)
  const int w   = blockIdx.x & ((1 << sh) - 1);
  const int g   = blockIdx.x >> sh;
  const int bm  = g*8 + (w & 7);
  const int bn  = w >> 3;

  const int srow  = tid >> 2;                   // 0..63 (row within chunk)
  const int gq    = (tid & 3) ^ ((tid >> 3) & 3);  // swizzled source unit
  const int skcol = gq << 3;                    // source k-offset (elements)
  const int swz   = quad ^ ((l15 >> 1) & 3);    // fragment read slot

  floatx4 acc[4][4] = {};

  for (int kt = 0; kt < K; kt += 32) {
    const bf16* aSrc; int lda, kof;
    if (kt < K0) { aSrc = A0; lda = K0;     kof = kt; }
    else         { aSrc = A1; lda = K - K0; kof = kt - K0; }
    #pragma unroll
    for (int c = 0; c < 2; c++) {     // A tile rows 0..63 / 64..127
      const bf16* gp = aSrc + (size_t)(bm*128 + c*64 + srow)*lda + kof + skcol;
      __builtin_amdgcn_global_load_lds(
          (const __attribute__((address_space(1))) void*)gp,
          (__attribute__((address_space(3))) void*)(As + c*2048 + tid*8),
          16, 0, 0);
    }
    #pragma unroll
    for (int c = 0; c < 2; c++) {     // B tile
      const bf16* gp = B + (size_t)(bn*128 + c*64 + srow)*K + kt + skcol;
      __builtin_amdgcn_global_load_lds(
          (const __attribute__((address_space(1))) void*)gp,
          (__attribute__((address_space(3))) void*)(Bs + c*2048 + tid*8),
          16, 0, 0);
    }
    __syncthreads();
    short8 a[4], b[4];
    #pragma unroll
    for (int i = 0; i < 4; i++) {
      a[i] = *(const short8*)&As[((wm*64 + i*16 + l15)*4 + swz)*8];
      b[i] = *(const short8*)&Bs[((wn*64 + i*16 + l15)*4 + swz)*8];
    }
    #pragma unroll
    for (int i = 0; i < 4; i++)
      #pragma unroll
      for (int j = 0; j < 4; j++)
        acc[i][j] = __builtin_amdgcn_mfma_f32_16x16x32_bf16(a[i], b[j], acc[i][j], 0, 0, 0);
    __syncthreads();
  }

  // epilogue: C/D layout col=lane&15, row=quad*4+reg
  const int row0 = bm*128 + wm*64 + quad*4;
  const int col0 = bn*128 + wn*64 + l15;
  const bool doRope = (EPI == 2) || (EPI == 3 && bn < 2);
  if (doRope) {
    // pair-channel constants, fixed per lane (col0&31 == l15)
    const int pp_e = l15 >> 1;        // j even
    const int pp_o = pp_e + 8;        // j odd
    const int par  = pp_e & 1;        // i-angle (0) vs j-angle (1)
    const float dv_e = __expf(-1.15129254650564f * (float)(pp_e >> 1));
    const float dv_o = __expf(-1.15129254650564f * (float)(pp_o >> 1));
    const float sgn = (l15 & 1) ? 1.f : -1.f;
    #pragma unroll
    for (int i = 0; i < 4; i++) {
      #pragma unroll
      for (int r = 0; r < 4; r++) {
        int row = row0 + i*16 + r;
        int l = row & (LL-1);
        float pos = par ? (float)((l & 127) + 1) : (float)((l >> 7) + 1);
        float ae = pos * dv_e, ao = pos * dv_o;
        float se = __sinf(ae), ce = __cosf(ae);
        float so = __sinf(ao), co = __cosf(ao);
        #pragma unroll
        for (int j = 0; j < 4; j++) {
          float s = (j & 1) ? so : se;
          float c = (j & 1) ? co : ce;
          float v = acc[i][j][r];
          v = v > 0.f ? v + 1.f : __expf(v);   // elu+1
          float p = __shfl_xor(v, 1, 64);      // pair partner channel
          float o = fmaf(v, c, sgn * p * s);
          int stride = (EPI == 3) ? 256 : N;
          C[(size_t)row*stride + (col0 + j*16)] = __float2bfloat16(o);
        }
      }
    }
  } else if (EPI == 3) {
    // v half: plain store to C2 at col-256, stride 256
    #pragma unroll
    for (int i = 0; i < 4; i++)
      #pragma unroll
      for (int j = 0; j < 4; j++)
        #pragma unroll
        for (int r = 0; r < 4; r++)
          C2[(size_t)(row0 + i*16 + r)*256 + (col0 - 256 + j*16)] =
              __float2bfloat16(acc[i][j][r]);
  } else {
    #pragma unroll
    for (int i = 0; i < 4; i++)
      #pragma unroll
      for (int j = 0; j < 4; j++)
        #pragma unroll
        for (int r = 0; r < 4; r++) {
          float v = acc[i][j][r];
          if (EPI == 1) v = fmaxf(v, 0.f);
          C[(size_t)(row0 + i*16 + r)*N + (col0 + j*16)] = __float2bfloat16(v);
        }
  }
}

// ---------------- KV partials: no atomics --------------------------------
#define KVPAD 36   // f32 row stride: 144 B = 16B-aligned, breaks bank cycle
__global__ __launch_bounds__(256) void kv_kernel(
    const bf16* __restrict__ Kr, const bf16* __restrict__ V,
    float* __restrict__ KVp, float* __restrict__ Ksp)
{
  __shared__ __align__(16) float Kf[128*KVPAD];  // 18 KB
  __shared__ __align__(16) float Vf[128*KVPAD];  // 18 KB
  const int nh = blockIdx.x;               // n*8+h
  const int n = nh >> 3, h = nh & 7;
  const int cs = blockIdx.y;               // 32 chunks of 512 rows
  const int s0 = cs << 9;
  const int tid = threadIdx.x;
  const int d = tid >> 3, e0 = (tid & 7) << 2;

  float acc0 = 0.f, acc1 = 0.f, acc2 = 0.f, acc3 = 0.f, ks = 0.f;

  for (int sub = 0; sub < 4; sub++) {
    const int sb = s0 + sub*128;
    #pragma unroll
    for (int u = tid; u < 512; u += 256) {
      int row = u >> 2, d0 = (u & 3) << 3;
      size_t g = (((size_t)(n*LL + sb + row)*NHD + h) << 5) + d0;
      short8 k8 = *(const short8*)(Kr + g);
      short8 v8 = *(const short8*)(V + g);
      float* kp = &Kf[row*KVPAD + d0];
      float* vp = &Vf[row*KVPAD + d0];
      float4 ka = {u2f((unsigned short)k8[0]), u2f((unsigned short)k8[1]),
                   u2f((unsigned short)k8[2]), u2f((unsigned short)k8[3])};
      float4 kb = {u2f((unsigned short)k8[4]), u2f((unsigned short)k8[5]),
                   u2f((unsigned short)k8[6]), u2f((unsigned short)k8[7])};
      float4 va = {u2f((unsigned short)v8[0]), u2f((unsigned short)v8[1]),
                   u2f((unsigned short)v8[2]), u2f((unsigned short)v8[3])};
      float4 vb = {u2f((unsigned short)v8[4]), u2f((unsigned short)v8[5]),
                   u2f((unsigned short)v8[6]), u2f((unsigned short)v8[7])};
      *(float4*)kp = ka; *(float4*)(kp+4) = kb;
      *(float4*)vp = va; *(float4*)(vp+4) = vb;
    }
    __syncthreads();
    #pragma unroll 8
    for (int ss = 0; ss < 128; ss++) {
      float kd = Kf[ss*KVPAD + d];                     // broadcast (8 lanes)
      float4 v4 = *(const float4*)&Vf[ss*KVPAD + e0];  // broadcast (8 lanes)
      acc0 = fmaf(kd, v4.x, acc0);
      acc1 = fmaf(kd, v4.y, acc1);
      acc2 = fmaf(kd, v4.z, acc2);
      acc3 = fmaf(kd, v4.w, acc3);
      ks += kd;
    }
    __syncthreads();
  }

  float* kvp = KVp + (((size_t)nh << 5) + cs) * 1024 + (tid << 2);
  kvp[0] = acc0; kvp[1] = acc1; kvp[2] = acc2; kvp[3] = acc3;
  if ((tid & 7) == 0) Ksp[(((size_t)nh << 5) + cs) * 32 + d] = ks;
}

// ---------------- reduce partials -> KV[nh][1024], Ksum[nh][32] ----------
__global__ __launch_bounds__(256) void reduce_kv_kernel(
    const float* __restrict__ KVp, const float* __restrict__ Ksp,
    float* __restrict__ KV, float* __restrict__ Ksum)
{
  const int nh = blockIdx.x;
  const int tid = threadIdx.x;
  float4 acc = {0.f,0.f,0.f,0.f};
  #pragma unroll 8
  for (int cs = 0; cs < 32; cs++) {
    float4 p = *(const float4*)(KVp + (((size_t)nh << 5) + cs) * 1024 + (tid << 2));
    acc.x += p.x; acc.y += p.y; acc.z += p.z; acc.w += p.w;
  }
  *(float4*)(KV + ((size_t)nh << 10) + (tid << 2)) = acc;
  if (tid < 32) {
    float s = 0.f;
    #pragma unroll 8
    for (int cs = 0; cs < 32; cs++)
      s += Ksp[(((size_t)nh << 5) + cs) * 32 + tid];
    Ksum[(nh << 5) + tid] = s;
  }
}

// ---------------- out[l,h,e] = (Q_h . KV_h[:,e]) / (Q_h . Ksum_h + eps) ---
__global__ __launch_bounds__(256) void attn_out_kernel(
    const bf16* __restrict__ Qr, const float* __restrict__ KV,
    const float* __restrict__ Ksum, bf16* __restrict__ Out)
{
  __shared__ float KVs[8192];
  __shared__ float Kss[256];
  __shared__ float Qs[16][256];
  const int blk = blockIdx.x;            // 4096 blocks, 16 rows each
  const int n = blk >> 10;               // 1024 blocks per batch
  const int tid = threadIdx.x;
  const size_t rowBase = (size_t)blk * 16;
  for (int i = tid; i < 8192; i += 256) KVs[i] = KV[((size_t)n << 13) + i];
  Kss[tid] = Ksum[(n << 8) + tid];
  #pragma unroll
  for (int it = 0; it < 2; it++) {
    int i = it*256 + tid;                // 8-elem unit, 512 units total
    short8 u = *(const short8*)(Qr + (rowBase << 8) + (size_t)i*8);
    float* qp = ((float*)Qs) + (size_t)i*8;
    #pragma unroll
    for (int j = 0; j < 8; j++) qp[j] = u2f((unsigned short)u[j]);
  }
  __syncthreads();
  const int h = tid >> 5, e = tid & 31;
  const float* kvh = &KVs[(h << 10) + e];
  const float* ksh = &Kss[h << 5];
  for (int r = 0; r < 16; r++) {
    const float* qh = &Qs[r][h << 5];
    float denom = 1e-6f;
    float num = 0.f;
    #pragma unroll
    for (int d = 0; d < 32; d++) {
      float qd = qh[d];
      denom = fmaf(qd, ksh[d], denom);
      num   = fmaf(qd, kvh[d << 5], num);
    }
    Out[((rowBase + r) << 8) + tid] = __float2bfloat16(num / denom);
  }
}

// ---------------- LayerNorm over 256, bf16 ws in/out, f32 params ---------
__global__ __launch_bounds__(256) void ln_kernel(
    const bf16* __restrict__ X, const float* __restrict__ g, const float* __restrict__ b,
    bf16* __restrict__ Out)
{
  __shared__ float ps[4], psq[4], stat[2];
  int row = blockIdx.x, tid = threadIdx.x;
  float v = __bfloat162float(X[((size_t)row << 8) + tid]);
  float s = v, sq = v*v;
  #pragma unroll
  for (int o = 32; o > 0; o >>= 1) {
    s  += __shfl_down(s, o, 64);
    sq += __shfl_down(sq, o, 64);
  }
  if ((tid & 63) == 0) { ps[tid>>6] = s; psq[tid>>6] = sq; }
  __syncthreads();
  if (tid == 0) {
    float S = ps[0]+ps[1]+ps[2]+ps[3];
    float SQ = psq[0]+psq[1]+psq[2]+psq[3];
    float mean = S * (1.f/256.f);
    float var = SQ * (1.f/256.f) - mean*mean;
    stat[0] = mean; stat[1] = rsqrtf(var + 1e-5f);
  }
  __syncthreads();
  float mean = stat[0], rstd = stat[1];
  Out[((size_t)row << 8) + tid] = __float2bfloat16(
      (v - mean)*rstd*g[tid] + b[tid]);
}

// ---------------- final: out = x + LN(h2), f32 x/out ---------------------
__global__ __launch_bounds__(256) void ln_add_kernel(
    const bf16* __restrict__ X, const float* __restrict__ g, const float* __restrict__ b,
    const float* __restrict__ xin, float* __restrict__ Out)
{
  __shared__ float ps[4], psq[4], stat[2];
  int row = blockIdx.x, tid = threadIdx.x;
  size_t idx = ((size_t)row << 8) + tid;
  float v = __bfloat162float(X[idx]);
  float s = v, sq = v*v;
  #pragma unroll
  for (int o = 32; o > 0; o >>= 1) {
    s  += __shfl_down(s, o, 64);
    sq += __shfl_down(sq, o, 64);
  }
  if ((tid & 63) == 0) { ps[tid>>6] = s; psq[tid>>6] = sq; }
  __syncthreads();
  if (tid == 0) {
    float S = ps[0]+ps[1]+ps[2]+ps[3];
    float SQ = psq[0]+psq[1]+psq[2]+psq[3];
    float mean = S * (1.f/256.f);
    float var = SQ * (1.f/256.f) - mean*mean;
    stat[0] = mean; stat[1] = rsqrtf(var + 1e-5f);
  }
  __syncthreads();
  float mean = stat[0], rstd = stat[1];
  float lnv = (v - mean)*rstd*g[tid] + b[tid];
  Out[idx] = xin[idx] + lnv;
}

extern "C" void kernel_launch(void* const* d_in, const int* in_sizes, int n_in,
                              void* d_out, int out_size, void* d_ws, size_t ws_size,
                              hipStream_t stream) {
  const float* x   = (const float*)d_in[0];
  const float* src = (const float*)d_in[1];
  const float* Wq  = (const float*)d_in[2];
  const float* Wk  = (const float*)d_in[3];
  const float* Wv  = (const float*)d_in[4];
  const float* Wm  = (const float*)d_in[5];
  const float* W1  = (const float*)d_in[6];
  const float* W2  = (const float*)d_in[7];
  const float* g1  = (const float*)d_in[8];
  const float* b1  = (const float*)d_in[9];
  const float* g2  = (const float*)d_in[10];
  const float* b2  = (const float*)d_in[11];
  float* out = (float*)d_out;

  bf16* ws = (bf16*)d_ws;
  const size_t BUFH = (size_t)MROWS * CC;   // 16,777,216 bf16 = 32 MB
  bf16* R0 = ws;               // xb (live until W1 gemm)
  bf16* R1 = ws + BUFH;        // sb -> q -> h1(lo)
  bf16* R2 = ws + 2*BUFH;      // k -> attn -> h1(hi)
  bf16* R3 = ws + 3*BUFH;      // v -> msg -> h2
  bf16* WB = ws + 4*BUFH;      // bf16 weights, 655360 elems (1.25 MB)
  bf16* wq = WB, *wk = WB+65536, *wv = WB+131072, *wm = WB+196608,
      *w1 = WB+262144, *w2 = WB+524288;
  float* KV   = (float*)(WB + 655360);      // 32768 f32
  float* Ksum = KV + NB*NHD*DH*DH;          // 1024 f32
  // KV partials live in d_out (64 MB, overwritten only by final ln_add):
  float* KVp = out;                         // 32*32*1024 f32 = 4 MB
  float* Ksp = out + 32*32*1024;            // 32*32*32 f32 = 128 KB

  dim3 blk(256);
  const int n8 = MROWS*CC/8;
  convert_kernel<<<(n8+255)/256, blk, 0, stream>>>(x,   R0, n8);
  convert_kernel<<<(n8+255)/256, blk, 0, stream>>>(src, R1, n8);
  convert_weights_kernel<<<320, blk, 0, stream>>>(Wq, Wk, Wv, Wm, W1, W2, WB);

  const int G256 = (MROWS/128)*(CC/128);    // 1024 blocks
  const int G512 = (MROWS/128)*(2*CC/128);  // 2048 blocks
  // fused: [k|v] = sb @ [wk;wv]^T -> k(rope)->R2, v->R3 (wk,wv contiguous)
  gemm_m97<3><<<G512, blk, 0, stream>>>(R1, CC, nullptr, wk, R2, R3, MROWS, 2*CC, CC);
  // KV + Ksum via partials (no atomics)
  kv_kernel<<<dim3(NB*NHD, 32), blk, 0, stream>>>(R2, R3, KVp, Ksp);
  reduce_kv_kernel<<<NB*NHD, blk, 0, stream>>>(KVp, Ksp, KV, Ksum);
  // q = rope(elu(xb@Wq^T)+1) -> R1 (sb dead)
  gemm_m97<2><<<G256, blk, 0, stream>>>(R0, CC, nullptr, wq, R1, nullptr, MROWS, CC, CC);
  // attn: q(R1) -> R2 (k dead)
  attn_out_kernel<<<MROWS/16, blk, 0, stream>>>(R1, KV, Ksum, R2);
  // msg = LN1(attn @ Wm^T): attn(R2) -> R3 (v dead)
  gemm_m97<0><<<G256, blk, 0, stream>>>(R2, CC, nullptr, wm, R3, nullptr, MROWS, CC, CC);
  ln_kernel<<<MROWS, blk, 0, stream>>>(R3, g1, b1, R3);
  // h1 = relu([xb(R0) | msg(R3)] @ W1^T) -> R1..R2 (64 MB contiguous)
  gemm_m97<1><<<G512, blk, 0, stream>>>(R0, CC, R3, w1, R1, nullptr, MROWS, 2*CC, 2*CC);
  // h2 = h1(R1,K=512) @ W2^T -> R3 (msg dead)
  gemm_m97<0><<<G256, blk, 0, stream>>>(nullptr, 0, R1, w2, R3, nullptr, MROWS, CC, 2*CC);
  // out = x + LN2(h2)
  ln_add_kernel<<<MROWS, blk, 0, stream>>>(R3, g2, b2, x, out);
}

// Round 10
// 483.584 us; speedup vs baseline: 1.2656x; 1.1133x over previous
//
#include <hip/hip_runtime.h>
#include <hip/hip_bf16.h>
#include <math.h>

#define NB 4
#define LL 16384
#define CC 256
#define NHD 8
#define DH 32
#define MROWS (NB*LL)   // 65536

typedef __hip_bfloat16 bf16;
typedef __attribute__((ext_vector_type(8))) short short8;
typedef __attribute__((ext_vector_type(4))) float floatx4;

__device__ __forceinline__ float u2f(unsigned short u) {
  return __uint_as_float(((unsigned)u) << 16);
}
__device__ __forceinline__ unsigned short f2u(float f) {
  bf16 t = __float2bfloat16(f);
  unsigned short u;
  __builtin_memcpy(&u, &t, 2);
  return u;
}

// ---------------- f32 -> bf16 bulk convert (8 elems/thread) --------------
__global__ __launch_bounds__(256) void convert_kernel(
    const float* __restrict__ in, bf16* __restrict__ out, int n8)
{
  int i = blockIdx.x*256 + threadIdx.x;
  if (i >= n8) return;
  const float4* p = (const float4*)in + (size_t)i*2;
  float4 f0 = p[0], f1 = p[1];
  unsigned short t[8] = {f2u(f0.x),f2u(f0.y),f2u(f0.z),f2u(f0.w),
                         f2u(f1.x),f2u(f1.y),f2u(f1.z),f2u(f1.w)};
  *(uint4*)(out + (size_t)i*8) = *(uint4*)t;
}

// ---------------- all weights f32 -> bf16, one dispatch ------------------
__global__ __launch_bounds__(256) void convert_weights_kernel(
    const float* __restrict__ Wq, const float* __restrict__ Wk,
    const float* __restrict__ Wv, const float* __restrict__ Wm,
    const float* __restrict__ W1, const float* __restrict__ W2,
    bf16* __restrict__ dst)
{
  int i = blockIdx.x*256 + threadIdx.x;    // 8-elem unit; total 81920 units
  const float* src; int off8;
  if      (i < 8192)  { src = Wq; off8 = i; }
  else if (i < 16384) { src = Wk; off8 = i-8192; }
  else if (i < 24576) { src = Wv; off8 = i-16384; }
  else if (i < 32768) { src = Wm; off8 = i-24576; }
  else if (i < 65536) { src = W1; off8 = i-32768; }
  else                { src = W2; off8 = i-65536; }
  const float4* p = (const float4*)src + (size_t)off8*2;
  float4 f0 = p[0], f1 = p[1];
  unsigned short t[8] = {f2u(f0.x),f2u(f0.y),f2u(f0.z),f2u(f0.w),
                         f2u(f1.x),f2u(f1.y),f2u(f1.z),f2u(f1.w)};
  *(uint4*)(dst + (size_t)i*8) = *(uint4*)t;
}

// ---------------- m97-style 4-wave 128x128 MFMA GEMM ---------------------
// C[M,N] = epi( A[M,K] @ B[N,K]^T ), all bf16.  BK=32.
// Round-0 proven staging choreography (A AND B via global_load_lds, one
// vmcnt-draining __syncthreads per step) + round-8 proven XOR swizzle on
// BOTH tiles: LDS dest linear (unit u at u*16B), global source unit
// gq = q ^ ((row>>1)&3) (permutation inside each row's 64B segment ->
// same coalescing), fragment read slot swz = quad ^ ((l15>>1)&3).
// Measured (r8): SQ_LDS_BANK_CONFLICT 4.19M -> 0.
// EPI: 0 none, 1 relu, 2 elu+1+RoPE (N=256),
//      3 fused k|v: bn<2 -> rope to C (stride 256), bn>=2 -> plain to C2.
template<int EPI>
__global__ __launch_bounds__(256) void gemm_m97(
    const bf16* __restrict__ A0, int K0, const bf16* __restrict__ A1,
    const bf16* __restrict__ B, bf16* __restrict__ C, bf16* __restrict__ C2,
    int M, int N, int K)
{
  __shared__ __align__(16) unsigned short As[128*32];  // 8 KB
  __shared__ __align__(16) unsigned short Bs[128*32];  // 8 KB
  const int tid  = threadIdx.x;
  const int lane = tid & 63, wave = tid >> 6;
  const int wm = wave & 1, wn = wave >> 1;
  const int l15 = lane & 15, quad = lane >> 4;

  // swizzle: blocks with same bm, all bn sit 8 apart -> same XCD L2 shares A
  const int nbn = N >> 7;                       // 2 or 4
  const int sh  = (nbn == 2) ? 4 : 5;           // log2(8*nbn)
  const int w   = blockIdx.x & ((1 << sh) - 1);
  const int g   = blockIdx.x >> sh;
  const int bm  = g*8 + (w & 7);
  const int bn  = w >> 3;

  const int srow  = tid >> 2;                   // 0..63 (row within chunk)
  const int gq    = (tid & 3) ^ ((tid >> 3) & 3);  // swizzled source unit
  const int skcol = gq << 3;                    // source k-offset (elements)
  const int swz   = quad ^ ((l15 >> 1) & 3);    // fragment read slot

  floatx4 acc[4][4] = {};

  for (int kt = 0; kt < K; kt += 32) {
    const bf16* aSrc; int lda, kof;
    if (kt < K0) { aSrc = A0; lda = K0;     kof = kt; }
    else         { aSrc = A1; lda = K - K0; kof = kt - K0; }
    #pragma unroll
    for (int c = 0; c < 2; c++) {     // A tile rows 0..63 / 64..127
      const bf16* gp = aSrc + (size_t)(bm*128 + c*64 + srow)*lda + kof + skcol;
      __builtin_amdgcn_global_load_lds(
          (const __attribute__((address_space(1))) void*)gp,
          (__attribute__((address_space(3))) void*)(As + c*2048 + tid*8),
          16, 0, 0);
    }
    #pragma unroll
    for (int c = 0; c < 2; c++) {     // B tile
      const bf16* gp = B + (size_t)(bn*128 + c*64 + srow)*K + kt + skcol;
      __builtin_amdgcn_global_load_lds(
          (const __attribute__((address_space(1))) void*)gp,
          (__attribute__((address_space(3))) void*)(Bs + c*2048 + tid*8),
          16, 0, 0);
    }
    __syncthreads();
    short8 a[4], b[4];
    #pragma unroll
    for (int i = 0; i < 4; i++) {
      a[i] = *(const short8*)&As[((wm*64 + i*16 + l15)*4 + swz)*8];
      b[i] = *(const short8*)&Bs[((wn*64 + i*16 + l15)*4 + swz)*8];
    }
    #pragma unroll
    for (int i = 0; i < 4; i++)
      #pragma unroll
      for (int j = 0; j < 4; j++)
        acc[i][j] = __builtin_amdgcn_mfma_f32_16x16x32_bf16(a[i], b[j], acc[i][j], 0, 0, 0);
    __syncthreads();
  }

  // epilogue: C/D layout col=lane&15, row=quad*4+reg
  const int row0 = bm*128 + wm*64 + quad*4;
  const int col0 = bn*128 + wn*64 + l15;
  const bool doRope = (EPI == 2) || (EPI == 3 && bn < 2);
  if (doRope) {
    // pair-channel constants, fixed per lane (col0&31 == l15)
    const int pp_e = l15 >> 1;        // j even
    const int pp_o = pp_e + 8;        // j odd
    const int par  = pp_e & 1;        // i-angle (0) vs j-angle (1)
    const float dv_e = __expf(-1.15129254650564f * (float)(pp_e >> 1));
    const float dv_o = __expf(-1.15129254650564f * (float)(pp_o >> 1));
    const float sgn = (l15 & 1) ? 1.f : -1.f;
    #pragma unroll
    for (int i = 0; i < 4; i++) {
      #pragma unroll
      for (int r = 0; r < 4; r++) {
        int row = row0 + i*16 + r;
        int l = row & (LL-1);
        float pos = par ? (float)((l & 127) + 1) : (float)((l >> 7) + 1);
        float ae = pos * dv_e, ao = pos * dv_o;
        float se = __sinf(ae), ce = __cosf(ae);
        float so = __sinf(ao), co = __cosf(ao);
        #pragma unroll
        for (int j = 0; j < 4; j++) {
          float s = (j & 1) ? so : se;
          float c = (j & 1) ? co : ce;
          float v = acc[i][j][r];
          v = v > 0.f ? v + 1.f : __expf(v);   // elu+1
          float p = __shfl_xor(v, 1, 64);      // pair partner channel
          float o = fmaf(v, c, sgn * p * s);
          int stride = (EPI == 3) ? 256 : N;
          C[(size_t)row*stride + (col0 + j*16)] = __float2bfloat16(o);
        }
      }
    }
  } else if (EPI == 3) {
    // v half: plain store to C2 at col-256, stride 256
    #pragma unroll
    for (int i = 0; i < 4; i++)
      #pragma unroll
      for (int j = 0; j < 4; j++)
        #pragma unroll
        for (int r = 0; r < 4; r++)
          C2[(size_t)(row0 + i*16 + r)*256 + (col0 - 256 + j*16)] =
              __float2bfloat16(acc[i][j][r]);
  } else {
    #pragma unroll
    for (int i = 0; i < 4; i++)
      #pragma unroll
      for (int j = 0; j < 4; j++)
        #pragma unroll
        for (int r = 0; r < 4; r++) {
          float v = acc[i][j][r];
          if (EPI == 1) v = fmaxf(v, 0.f);
          C[(size_t)(row0 + i*16 + r)*N + (col0 + j*16)] = __float2bfloat16(v);
        }
  }
}

// ---------------- KV partials: no atomics --------------------------------
#define KVPAD 36   // f32 row stride: 144 B = 16B-aligned, breaks bank cycle
__global__ __launch_bounds__(256) void kv_kernel(
    const bf16* __restrict__ Kr, const bf16* __restrict__ V,
    float* __restrict__ KVp, float* __restrict__ Ksp)
{
  __shared__ __align__(16) float Kf[128*KVPAD];  // 18 KB
  __shared__ __align__(16) float Vf[128*KVPAD];  // 18 KB
  const int nh = blockIdx.x;               // n*8+h
  const int n = nh >> 3, h = nh & 7;
  const int cs = blockIdx.y;               // 32 chunks of 512 rows
  const int s0 = cs << 9;
  const int tid = threadIdx.x;
  const int d = tid >> 3, e0 = (tid & 7) << 2;

  float acc0 = 0.f, acc1 = 0.f, acc2 = 0.f, acc3 = 0.f, ks = 0.f;

  for (int sub = 0; sub < 4; sub++) {
    const int sb = s0 + sub*128;
    #pragma unroll
    for (int u = tid; u < 512; u += 256) {
      int row = u >> 2, d0 = (u & 3) << 3;
      size_t g = (((size_t)(n*LL + sb + row)*NHD + h) << 5) + d0;
      short8 k8 = *(const short8*)(Kr + g);
      short8 v8 = *(const short8*)(V + g);
      float* kp = &Kf[row*KVPAD + d0];
      float* vp = &Vf[row*KVPAD + d0];
      float4 ka = {u2f((unsigned short)k8[0]), u2f((unsigned short)k8[1]),
                   u2f((unsigned short)k8[2]), u2f((unsigned short)k8[3])};
      float4 kb = {u2f((unsigned short)k8[4]), u2f((unsigned short)k8[5]),
                   u2f((unsigned short)k8[6]), u2f((unsigned short)k8[7])};
      float4 va = {u2f((unsigned short)v8[0]), u2f((unsigned short)v8[1]),
                   u2f((unsigned short)v8[2]), u2f((unsigned short)v8[3])};
      float4 vb = {u2f((unsigned short)v8[4]), u2f((unsigned short)v8[5]),
                   u2f((unsigned short)v8[6]), u2f((unsigned short)v8[7])};
      *(float4*)kp = ka; *(float4*)(kp+4) = kb;
      *(float4*)vp = va; *(float4*)(vp+4) = vb;
    }
    __syncthreads();
    #pragma unroll 8
    for (int ss = 0; ss < 128; ss++) {
      float kd = Kf[ss*KVPAD + d];                     // broadcast (8 lanes)
      float4 v4 = *(const float4*)&Vf[ss*KVPAD + e0];  // broadcast (8 lanes)
      acc0 = fmaf(kd, v4.x, acc0);
      acc1 = fmaf(kd, v4.y, acc1);
      acc2 = fmaf(kd, v4.z, acc2);
      acc3 = fmaf(kd, v4.w, acc3);
      ks += kd;
    }
    __syncthreads();
  }

  float* kvp = KVp + (((size_t)nh << 5) + cs) * 1024 + (tid << 2);
  kvp[0] = acc0; kvp[1] = acc1; kvp[2] = acc2; kvp[3] = acc3;
  if ((tid & 7) == 0) Ksp[(((size_t)nh << 5) + cs) * 32 + d] = ks;
}

// ---------------- reduce partials -> KV[nh][1024], Ksum[nh][32] ----------
__global__ __launch_bounds__(256) void reduce_kv_kernel(
    const float* __restrict__ KVp, const float* __restrict__ Ksp,
    float* __restrict__ KV, float* __restrict__ Ksum)
{
  const int nh = blockIdx.x;
  const int tid = threadIdx.x;
  float4 acc = {0.f,0.f,0.f,0.f};
  #pragma unroll 8
  for (int cs = 0; cs < 32; cs++) {
    float4 p = *(const float4*)(KVp + (((size_t)nh << 5) + cs) * 1024 + (tid << 2));
    acc.x += p.x; acc.y += p.y; acc.z += p.z; acc.w += p.w;
  }
  *(float4*)(KV + ((size_t)nh << 10) + (tid << 2)) = acc;
  if (tid < 32) {
    float s = 0.f;
    #pragma unroll 8
    for (int cs = 0; cs < 32; cs++)
      s += Ksp[(((size_t)nh << 5) + cs) * 32 + tid];
    Ksum[(nh << 5) + tid] = s;
  }
}

// ---------------- out[l,h,e] = (Q_h . KV_h[:,e]) / (Q_h . Ksum_h + eps) ---
__global__ __launch_bounds__(256) void attn_out_kernel(
    const bf16* __restrict__ Qr, const float* __restrict__ KV,
    const float* __restrict__ Ksum, bf16* __restrict__ Out)
{
  __shared__ float KVs[8192];
  __shared__ float Kss[256];
  __shared__ float Qs[16][256];
  const int blk = blockIdx.x;            // 4096 blocks, 16 rows each
  const int n = blk >> 10;               // 1024 blocks per batch
  const int tid = threadIdx.x;
  const size_t rowBase = (size_t)blk * 16;
  for (int i = tid; i < 8192; i += 256) KVs[i] = KV[((size_t)n << 13) + i];
  Kss[tid] = Ksum[(n << 8) + tid];
  #pragma unroll
  for (int it = 0; it < 2; it++) {
    int i = it*256 + tid;                // 8-elem unit, 512 units total
    short8 u = *(const short8*)(Qr + (rowBase << 8) + (size_t)i*8);
    float* qp = ((float*)Qs) + (size_t)i*8;
    #pragma unroll
    for (int j = 0; j < 8; j++) qp[j] = u2f((unsigned short)u[j]);
  }
  __syncthreads();
  const int h = tid >> 5, e = tid & 31;
  const float* kvh = &KVs[(h << 10) + e];
  const float* ksh = &Kss[h << 5];
  for (int r = 0; r < 16; r++) {
    const float* qh = &Qs[r][h << 5];
    float denom = 1e-6f;
    float num = 0.f;
    #pragma unroll
    for (int d = 0; d < 32; d++) {
      float qd = qh[d];
      denom = fmaf(qd, ksh[d], denom);
      num   = fmaf(qd, kvh[d << 5], num);
    }
    Out[((rowBase + r) << 8) + tid] = __float2bfloat16(num / denom);
  }
}

// ---------------- LayerNorm over 256: 1 wave/row, 4 rows/block -----------
// No LDS, no barriers: in-wave shfl_xor butterfly; 8-16B/lane loads/stores.
__global__ __launch_bounds__(256) void ln_kernel(
    const bf16* __restrict__ X, const float* __restrict__ g, const float* __restrict__ b,
    bf16* __restrict__ Out)
{
  const int tid = threadIdx.x;
  const int wave = tid >> 6, lane = tid & 63;
  const size_t row = (size_t)blockIdx.x*4 + wave;
  const size_t base = (row << 8) + lane*4;
  ushort4 u = *(const ushort4*)(X + base);
  float v0 = u2f(u.x), v1 = u2f(u.y), v2 = u2f(u.z), v3 = u2f(u.w);
  float s  = v0 + v1 + v2 + v3;
  float sq = v0*v0 + v1*v1 + v2*v2 + v3*v3;
  #pragma unroll
  for (int o = 1; o < 64; o <<= 1) {
    s  += __shfl_xor(s,  o, 64);
    sq += __shfl_xor(sq, o, 64);
  }
  float mean = s * (1.f/256.f);
  float var  = sq * (1.f/256.f) - mean*mean;
  float rstd = rsqrtf(var + 1e-5f);
  float4 gv = *(const float4*)(g + lane*4);
  float4 bv = *(const float4*)(b + lane*4);
  unsigned short t[4] = {
    f2u((v0 - mean)*rstd*gv.x + bv.x),
    f2u((v1 - mean)*rstd*gv.y + bv.y),
    f2u((v2 - mean)*rstd*gv.z + bv.z),
    f2u((v3 - mean)*rstd*gv.w + bv.w)};
  *(uint2*)(Out + base) = *(uint2*)t;
}

// ---------------- final: out = x + LN(h2): 1 wave/row, 4 rows/block ------
__global__ __launch_bounds__(256) void ln_add_kernel(
    const bf16* __restrict__ X, const float* __restrict__ g, const float* __restrict__ b,
    const float* __restrict__ xin, float* __restrict__ Out)
{
  const int tid = threadIdx.x;
  const int wave = tid >> 6, lane = tid & 63;
  const size_t row = (size_t)blockIdx.x*4 + wave;
  const size_t base = (row << 8) + lane*4;
  ushort4 u = *(const ushort4*)(X + base);
  float v0 = u2f(u.x), v1 = u2f(u.y), v2 = u2f(u.z), v3 = u2f(u.w);
  float s  = v0 + v1 + v2 + v3;
  float sq = v0*v0 + v1*v1 + v2*v2 + v3*v3;
  #pragma unroll
  for (int o = 1; o < 64; o <<= 1) {
    s  += __shfl_xor(s,  o, 64);
    sq += __shfl_xor(sq, o, 64);
  }
  float mean = s * (1.f/256.f);
  float var  = sq * (1.f/256.f) - mean*mean;
  float rstd = rsqrtf(var + 1e-5f);
  float4 gv = *(const float4*)(g + lane*4);
  float4 bv = *(const float4*)(b + lane*4);
  float4 xv = *(const float4*)(xin + base);
  float4 ov = {
    xv.x + (v0 - mean)*rstd*gv.x + bv.x,
    xv.y + (v1 - mean)*rstd*gv.y + bv.y,
    xv.z + (v2 - mean)*rstd*gv.z + bv.z,
    xv.w + (v3 - mean)*rstd*gv.w + bv.w};
  *(float4*)(Out + base) = ov;
}

extern "C" void kernel_launch(void* const* d_in, const int* in_sizes, int n_in,
                              void* d_out, int out_size, void* d_ws, size_t ws_size,
                              hipStream_t stream) {
  const float* x   = (const float*)d_in[0];
  const float* src = (const float*)d_in[1];
  const float* Wq  = (const float*)d_in[2];
  const float* Wk  = (const float*)d_in[3];
  const float* Wv  = (const float*)d_in[4];
  const float* Wm  = (const float*)d_in[5];
  const float* W1  = (const float*)d_in[6];
  const float* W2  = (const float*)d_in[7];
  const float* g1  = (const float*)d_in[8];
  const float* b1  = (const float*)d_in[9];
  const float* g2  = (const float*)d_in[10];
  const float* b2  = (const float*)d_in[11];
  float* out = (float*)d_out;

  bf16* ws = (bf16*)d_ws;
  const size_t BUFH = (size_t)MROWS * CC;   // 16,777,216 bf16 = 32 MB
  bf16* R0 = ws;               // xb (live until W1 gemm)
  bf16* R1 = ws + BUFH;        // sb -> q -> h1(lo)
  bf16* R2 = ws + 2*BUFH;      // k -> attn -> h1(hi)
  bf16* R3 = ws + 3*BUFH;      // v -> msg -> h2
  bf16* WB = ws + 4*BUFH;      // bf16 weights, 655360 elems (1.25 MB)
  bf16* wq = WB, *wk = WB+65536, *wv = WB+131072, *wm = WB+196608,
      *w1 = WB+262144, *w2 = WB+524288;
  float* KV   = (float*)(WB + 655360);      // 32768 f32
  float* Ksum = KV + NB*NHD*DH*DH;          // 1024 f32
  // KV partials live in d_out (64 MB, overwritten only by final ln_add):
  float* KVp = out;                         // 32*32*1024 f32 = 4 MB
  float* Ksp = out + 32*32*1024;            // 32*32*32 f32 = 128 KB

  dim3 blk(256);
  const int n8 = MROWS*CC/8;
  convert_kernel<<<(n8+255)/256, blk, 0, stream>>>(x,   R0, n8);
  convert_kernel<<<(n8+255)/256, blk, 0, stream>>>(src, R1, n8);
  convert_weights_kernel<<<320, blk, 0, stream>>>(Wq, Wk, Wv, Wm, W1, W2, WB);

  const int G256 = (MROWS/128)*(CC/128);    // 1024 blocks
  const int G512 = (MROWS/128)*(2*CC/128);  // 2048 blocks
  // fused: [k|v] = sb @ [wk;wv]^T -> k(rope)->R2, v->R3 (wk,wv contiguous)
  gemm_m97<3><<<G512, blk, 0, stream>>>(R1, CC, nullptr, wk, R2, R3, MROWS, 2*CC, CC);
  // KV + Ksum via partials (no atomics)
  kv_kernel<<<dim3(NB*NHD, 32), blk, 0, stream>>>(R2, R3, KVp, Ksp);
  reduce_kv_kernel<<<NB*NHD, blk, 0, stream>>>(KVp, Ksp, KV, Ksum);
  // q = rope(elu(xb@Wq^T)+1) -> R1 (sb dead)
  gemm_m97<2><<<G256, blk, 0, stream>>>(R0, CC, nullptr, wq, R1, nullptr, MROWS, CC, CC);
  // attn: q(R1) -> R2 (k dead)
  attn_out_kernel<<<MROWS/16, blk, 0, stream>>>(R1, KV, Ksum, R2);
  // msg = LN1(attn @ Wm^T): attn(R2) -> R3 (v dead)
  gemm_m97<0><<<G256, blk, 0, stream>>>(R2, CC, nullptr, wm, R3, nullptr, MROWS, CC, CC);
  ln_kernel<<<MROWS/4, blk, 0, stream>>>(R3, g1, b1, R3);
  // h1 = relu([xb(R0) | msg(R3)] @ W1^T) -> R1..R2 (64 MB contiguous)
  gemm_m97<1><<<G512, blk, 0, stream>>>(R0, CC, R3, w1, R1, nullptr, MROWS, 2*CC, 2*CC);
  // h2 = h1(R1,K=512) @ W2^T -> R3 (msg dead)
  gemm_m97<0><<<G256, blk, 0, stream>>>(nullptr, 0, R1, w2, R3, nullptr, MROWS, CC, 2*CC);
  // out = x + LN2(h2)
  ln_add_kernel<<<MROWS/4, blk, 0, stream>>>(R3, g2, b2, x, out);
}